// Round 5
// baseline (1204.739 us; speedup 1.0000x reference)
//
#include <hip/hip_runtime.h>

typedef _Float16 f16;
typedef f16 f16x8 __attribute__((ext_vector_type(8)));
typedef float f32x4 __attribute__((ext_vector_type(4)));

#define NB 16384
#define D 400
#define DP 416
#define NEXP 8
#define NTASK 10
#define NKT 13

#define MEMFENCE asm volatile("" ::: "memory")
#define BAR() do{ MEMFENCE; __builtin_amdgcn_s_barrier(); MEMFENCE; }while(0)
#define VM(N) asm volatile("s_waitcnt vmcnt(" #N ")" ::: "memory")
#define LGKM0 asm volatile("s_waitcnt lgkmcnt(0)" ::: "memory")

static __device__ __forceinline__ f32x4 mfma16x32(f16x8 a, f16x8 b, f32x4 c){
  return __builtin_amdgcn_mfma_f32_16x16x32_f16(a, b, c, 0, 0, 0);
}
static __device__ __forceinline__ void g2l(const void* g, void* l){
  __builtin_amdgcn_global_load_lds((const __attribute__((address_space(1))) void*)g,
      (__attribute__((address_space(3))) void*)l, 16, 0, 0);
}
static __device__ __forceinline__ f16x8 scale8(f16x8 a, f16 s){
  f16x8 r;
  #pragma unroll
  for (int e=0;e<8;e++) r[e] = a[e]*s;
  return r;
}

// ---- B "duo" staging: [16 rows][128B] pairs of 16-col tiles, chunk ^= row&7 ----
static __device__ __forceinline__ void stage_duo(const char* wbase, char* lds, int kt,
                                                 int t0, int dd, int h, int lane){
  const int r = lane >> 3, c = lane & 7, cg = c ^ r;
  g2l(wbase + (size_t)((t0 + dd*2 + (cg>>2))*16 + h*8 + r)*832 + (size_t)kt*64 + (cg&3)*16,
      lds + dd*2048 + h*1024);
}
// B-frag read: duo dloc, parity t; lane: col=l15, k=lhi*8+e
static __device__ __forceinline__ f16x8 rdB(const f16* buf, int dloc, int t, int lhi, int l15){
  return *(const f16x8*)(buf + dloc*1024 + l15*64 + ((((t*4+lhi) ^ (l15&7)))<<3));
}
// ---- A staging: halves of [16 rows][64B], chunk(16B) ^= row&3 ----
static __device__ __forceinline__ void stage_ah(const char* ab, char* adst, int kt,
                                                int a, int lane){
  const int r = lane >> 2, c = lane & 3, cg = c ^ (r & 3);
  g2l(ab + (size_t)(a*16 + r)*832 + (size_t)kt*64 + cg*16, adst + a*1024);
}
// A-frag read: global row R (block-local), k-chunk lhi
static __device__ __forceinline__ f16x8 rdA(const f16* abuf, int R, int lhi){
  return *(const f16x8*)(abuf + (R>>4)*512 + (R&15)*32 + ((lhi ^ (R&3))<<3));
}
// lact: [128][416] f16, 16B-chunk XOR swizzle on chunks<48
static __device__ __forceinline__ f16x8 rdL(const f16* lact, int r, int kt, int lhi){
  int q = kt*4 + lhi;
  int c = (q < 48) ? (q ^ (r&7)) : q;
  return *(const f16x8*)(lact + r*416 + (c<<3));
}
static __device__ __forceinline__ int lact_idx(int r, int col){
  int q = col >> 3;
  int c = (q < 48) ? (q ^ (r&7)) : q;
  return r*416 + (c<<3) + (col&7);
}

// stage helpers: B-only (26 halves over 8 waves)  W: wv<2 ? 4 : 3
static __device__ __forceinline__ void stageB8(const char* wb, char* buf, int kt,
                                               int wv, int lane){
  for (int u = wv; u < 26; u += 8) stage_duo(wb, buf, kt, 0, u>>1, u&1, lane);
}
// A+B (34 halves over 8 waves)  W: wv<2 ? 5 : 4
static __device__ __forceinline__ void stageAB8(const char* wb, const char* ab, char* buf,
                                                int kt, int wv, int lane){
  for (int u = wv; u < 34; u += 8){
    if (u < 26) stage_duo(wb, buf, kt, 0, u>>1, u&1, lane);
    else        stage_ah(ab, buf + 26*1024, kt, u-26, lane);
  }
}

// ---------------- prep kernels ----------------

__global__ void k_build_x(const float* __restrict__ obs, const float* __restrict__ act,
                          f16* __restrict__ x)
{
  int idx = blockIdx.x*256 + threadIdx.x;
  int b = idx >> 6, c = idx & 63;
  float v = 0.f;
  if (c < 39) v = obs[b*39 + c];
  else if (c < 43) v = act[b*4 + (c - 39)];
  x[idx] = (f16)v;
}

__global__ void k_transpose(const float* __restrict__ in, f16* __restrict__ out,
                            int K, int N, int Kpad, int Npad)
{
  __shared__ float t[32][33];
  int tx = threadIdx.x & 31, ty = threadIdx.x >> 5;
  int n0 = blockIdx.x*32, k0 = blockIdx.y*32;
  in  += (size_t)blockIdx.z * K * N;
  out += (size_t)blockIdx.z * Npad * Kpad;
  #pragma unroll
  for (int r=0;r<4;r++){
    int k = k0 + ty + r*8, nn = n0 + tx;
    t[ty + r*8][tx] = (k < K && nn < N) ? in[(size_t)k*N + nn] : 0.f;
  }
  __syncthreads();
  #pragma unroll
  for (int r=0;r<4;r++){
    int nn = n0 + ty + r*8, kp = k0 + tx;
    if (nn < Npad && kp < Kpad) out[(size_t)nn*Kpad + kp] = (f16)t[tx][ty + r*8];
  }
}

__global__ void k_val_pad(const float* __restrict__ in, f16* __restrict__ out)
{
  int idx = blockIdx.x*256 + threadIdx.x;
  if (idx >= NEXP*DP*DP) return;
  int c = idx % DP, r = (idx / DP) % DP, n = idx / (DP*DP);
  float v = (r < D && c < D) ? in[((size_t)n*D + r)*D + c] : 0.f;
  out[idx] = (f16)v;
}

__global__ void k_kq(const float* __restrict__ key_mat, const float* __restrict__ tq,
                     float* __restrict__ kq)
{
  __shared__ float tqs[NTASK*D];
  int n = blockIdx.x, tid = threadIdx.x;
  for (int i=tid;i<NTASK*D;i+=256) tqs[i] = tq[i];
  __syncthreads();
  float a0[NTASK], a1[NTASK];
  #pragma unroll
  for (int t=0;t<NTASK;t++){ a0[t]=0.f; a1[t]=0.f; }
  const float* km = key_mat + (size_t)n*D*D;
  for (int i=0;i<D;i++){
    float v0 = km[(size_t)i*D + tid];
    float v1 = (tid+256 < D) ? km[(size_t)i*D + tid + 256] : 0.f;
    #pragma unroll
    for (int t=0;t<NTASK;t++){
      float q = tqs[t*D + i];
      a0[t] += v0*q; a1[t] += v1*q;
    }
  }
  #pragma unroll
  for (int t=0;t<NTASK;t++){
    kq[(size_t)n*NTASK*DP + t*DP + tid] = a0[t];
    if (tid+256 < DP) kq[(size_t)n*NTASK*DP + t*DP + tid+256] = (tid+256 < D) ? a1[t] : 0.f;
  }
}

// ---------------- compute kernels ----------------
// 512 thr = 8 waves, BM=128. wave (rh=wv>>1, ch=wv&1): rows rh*32..+31, tiles ch*13..+12.

#define ZERO_ACC() do { _Pragma("unroll") for (int j=0;j<13;j++){ acc[0][j]=Z4; acc[1][j]=Z4; } } while(0)

#define MFMA26(a0_, a1_, BUF) do {                                              \
    __builtin_amdgcn_s_setprio(1);                                              \
    _Pragma("unroll")                                                           \
    for (int j=0;j<13;j++){                                                     \
      int tj = ch*13 + j;                                                       \
      f16x8 b = rdB((BUF), tj>>1, tj&1, lhi, l15);                              \
      acc[0][j] = mfma16x32((a0_), b, acc[0][j]);                               \
      acc[1][j] = mfma16x32((a1_), b, acc[1][j]);                               \
    }                                                                           \
    __builtin_amdgcn_s_setprio(0);                                              \
  } while(0)

// expert layer kernels: LDS = 2 x (26KB B + 8KB A) = 68KB -> 2 blocks/CU
__global__ __launch_bounds__(512,4) void k_exp1(
    const f16* __restrict__ h16, const f16* __restrict__ w1T, const float* __restrict__ b1s,
    f16* __restrict__ e1)
{
  __shared__ f16 buf[2][17408];   // B: 0..13311, A: 13312..17407
  const int tid = threadIdx.x, lane = tid & 63, wv = tid >> 6;
  const int l15 = lane & 15, lhi = lane >> 4;
  const int rh = wv >> 1, ch = wv & 1;
  const int n = blockIdx.x;
  const int rowbase = blockIdx.y * 128;
  const f32x4 Z4 = {0,0,0,0};
  f32x4 acc[2][13];

  const char* wb = (const char*)(w1T + (size_t)n*DP*DP);
  const char* ab = (const char*)h16 + (size_t)rowbase*832;

  ZERO_ACC();
  stageAB8(wb, ab, (char*)buf[0], 0, wv, lane);
  for (int kt=0; kt<NKT-1; kt++){
    stageAB8(wb, ab, (char*)buf[(kt+1)&1], kt+1, wv, lane);
    if (wv < 2) VM(5); else VM(4);
    BAR();
    const f16* bb = buf[kt&1]; const f16* ba = bb + 13312;
    f16x8 A0 = rdA(ba, rh*32 + l15, lhi);
    f16x8 A1 = rdA(ba, rh*32 + 16 + l15, lhi);
    MFMA26(A0, A1, bb);
    BAR();
  }
  VM(0); BAR();
  { const f16* bb = buf[0]; const f16* ba = bb + 13312;
    f16x8 A0 = rdA(ba, rh*32 + l15, lhi);
    f16x8 A1 = rdA(ba, rh*32 + 16 + l15, lhi);
    MFMA26(A0, A1, bb); }

  #pragma unroll
  for (int j=0;j<13;j++){
    int col = (ch*13+j)*16 + l15;
    float bv = (col<D)? b1s[n*D+col] : 0.f;
    #pragma unroll
    for (int ar=0;ar<2;ar++)
      #pragma unroll
      for (int rr=0;rr<4;rr++){
        float v = acc[ar][j][rr] + bv; v = v>0.f?v:0.f;
        e1[((size_t)n*NB + rowbase + rh*32+ar*16+lhi*4+rr)*DP + col] = (f16)v;
      }
  }
}

__global__ __launch_bounds__(512,4) void k_exp2(
    f16* __restrict__ e1 /* in: expert-L1 act, out (in-place): e2 */,
    const f16* __restrict__ w2T, const float* __restrict__ b2s,
    const float* __restrict__ kqg, const int* __restrict__ task,
    float* __restrict__ scores)
{
  __shared__ f16 buf[2][17408];
  __shared__ float psum[128][2];
  const int tid = threadIdx.x, lane = tid & 63, wv = tid >> 6;
  const int l15 = lane & 15, lhi = lane >> 4;
  const int rh = wv >> 1, ch = wv & 1;
  const int n = blockIdx.x;
  const int rowbase = blockIdx.y * 128;
  const f32x4 Z4 = {0,0,0,0};
  f32x4 acc[2][13];

  const char* wb = (const char*)(w2T + (size_t)n*DP*DP);
  const char* ab = (const char*)(e1 + ((size_t)n*NB + rowbase)*DP);

  ZERO_ACC();
  stageAB8(wb, ab, (char*)buf[0], 0, wv, lane);
  for (int kt=0; kt<NKT-1; kt++){
    stageAB8(wb, ab, (char*)buf[(kt+1)&1], kt+1, wv, lane);
    if (wv < 2) VM(5); else VM(4);
    BAR();
    const f16* bb = buf[kt&1]; const f16* ba = bb + 13312;
    f16x8 A0 = rdA(ba, rh*32 + l15, lhi);
    f16x8 A1 = rdA(ba, rh*32 + 16 + l15, lhi);
    MFMA26(A0, A1, bb);
    BAR();
  }
  VM(0); BAR();
  { const f16* bb = buf[0]; const f16* ba = bb + 13312;
    f16x8 A0 = rdA(ba, rh*32 + l15, lhi);
    f16x8 A1 = rdA(ba, rh*32 + 16 + l15, lhi);
    MFMA26(A0, A1, bb); }

  // epilogue: e2 (in-place over e1; this block's rows only) + score partials
  const float* kqp[2][4];
  const float* kqb = kqg + (size_t)n*NTASK*DP;
  #pragma unroll
  for (int ar=0;ar<2;ar++)
    #pragma unroll
    for (int rr=0;rr<4;rr++){
      int grow = rowbase + rh*32 + ar*16 + lhi*4 + rr;
      kqp[ar][rr] = kqb + (size_t)task[grow]*DP;
    }
  float p_[2][4] = {{0,0,0,0},{0,0,0,0}};
  #pragma unroll
  for (int j=0;j<13;j++){
    int col = (ch*13+j)*16 + l15;
    float bv = (col<D)? b2s[n*D+col] : 0.f;
    #pragma unroll
    for (int ar=0;ar<2;ar++)
      #pragma unroll
      for (int rr=0;rr<4;rr++){
        float v = acc[ar][j][rr] + bv; v = v>0.f?v:0.f;
        e1[((size_t)n*NB + rowbase + rh*32+ar*16+lhi*4+rr)*DP + col] = (f16)v;
        p_[ar][rr] += v * kqp[ar][rr][col];
      }
  }
  #pragma unroll
  for (int ar=0;ar<2;ar++)
    #pragma unroll
    for (int rr=0;rr<4;rr++){
      float p = p_[ar][rr];
      p += __shfl_xor(p, 1, 64);
      p += __shfl_xor(p, 2, 64);
      p += __shfl_xor(p, 4, 64);
      p += __shfl_xor(p, 8, 64);
      if (l15 == 0) psum[rh*32+ar*16+lhi*4+rr][ch] = p;
    }
  __syncthreads();
  if (tid < 128) scores[(size_t)(rowbase + tid)*NEXP + n] = psum[tid][0] + psum[tid][1];
}

__global__ __launch_bounds__(512,2) void k_backbone(
    const f16* __restrict__ x, const f16* __restrict__ w1T, const float* __restrict__ b1,
    const f16* __restrict__ w2T, const float* __restrict__ b2, f16* __restrict__ h16)
{
  __shared__ f16 bufB[2][13*1024];
  __shared__ f16 lact[128*416];
  const int tid = threadIdx.x, lane = tid & 63, wv = tid >> 6;
  const int l15 = lane & 15, lhi = lane >> 4;
  const int rh = wv >> 1, ch = wv & 1;
  const int rowbase = blockIdx.x * 128;
  const f32x4 Z4 = {0,0,0,0};
  f32x4 acc[2][13];

  // GEMM1: K=64. stage all 26 tiles flat (2KB each) across bufB[0]+bufB[1]
  { int r = lane>>3, c = lane&7, cg = c ^ r;
    for (int u = wv; u < 52; u += 8){
      int dd = u>>1, h = u&1;
      g2l((const char*)w1T + (size_t)(dd*16 + h*8 + r)*128 + cg*16,
          (char*)bufB[0] + dd*2048 + h*1024);
    }
  }
  ZERO_ACC();
  const f16* Ab = x + (size_t)(rowbase + rh*32 + l15)*64;
  __syncthreads();
  #pragma unroll
  for (int kt=0; kt<2; kt++){
    f16x8 a0 = *(const f16x8*)(Ab + kt*32 + lhi*8);
    f16x8 a1 = *(const f16x8*)(Ab + 16*64 + kt*32 + lhi*8);
    __builtin_amdgcn_s_setprio(1);
    #pragma unroll
    for (int j=0;j<13;j++){
      int tj = ch*13 + j;
      f16x8 b = rdB(bufB[0], tj, kt, lhi, l15);
      acc[0][j] = mfma16x32(a0, b, acc[0][j]);
      acc[1][j] = mfma16x32(a1, b, acc[1][j]);
    }
    __builtin_amdgcn_s_setprio(0);
  }
  BAR();                                   // all done reading GEMM1 tiles
  stageB8((const char*)w2T, (char*)bufB[0], 0, wv, lane);
  #pragma unroll
  for (int j=0;j<13;j++){
    int col = (ch*13+j)*16 + l15;
    float bv = (col<D)? b1[col] : 0.f;
    #pragma unroll
    for (int ar=0;ar<2;ar++)
      #pragma unroll
      for (int rr=0;rr<4;rr++){
        float v = acc[ar][j][rr] + bv; v = v>0.f?v:0.f;
        lact[lact_idx(rh*32+ar*16+lhi*4+rr, col)] = (f16)v;
      }
  }
  LGKM0; BAR();                            // lact visible; kt0 prefetch NOT drained

  // GEMM2: K=416, A from lact, counted-vmcnt 2-barrier loop
  ZERO_ACC();
  for (int kt=0; kt<NKT-1; kt++){
    stageB8((const char*)w2T, (char*)bufB[(kt+1)&1], kt+1, wv, lane);
    if (wv < 2) VM(4); else VM(3);
    BAR();
    f16x8 a0 = rdL(lact, rh*32 + l15, kt, lhi);
    f16x8 a1 = rdL(lact, rh*32 + 16 + l15, kt, lhi);
    MFMA26(a0, a1, bufB[kt&1]);
    BAR();
  }
  VM(0); BAR();
  { f16x8 a0 = rdL(lact, rh*32 + l15, 12, lhi);
    f16x8 a1 = rdL(lact, rh*32 + 16 + l15, 12, lhi);
    MFMA26(a0, a1, bufB[0]); }

  #pragma unroll
  for (int j=0;j<13;j++){
    int col = (ch*13+j)*16 + l15;
    float bv = (col<D)? b2[col] : 0.f;
    #pragma unroll
    for (int ar=0;ar<2;ar++)
      #pragma unroll
      for (int rr=0;rr<4;rr++){
        float v = acc[ar][j][rr] + bv; v = v>0.f?v:0.f;
        h16[(size_t)(rowbase + rh*32+ar*16+lhi*4+rr)*DP + col] = (f16)v;
      }
  }
}

// attn: softmax + 8 weighted value-GEMMs -> ti16. 256 thr, 4 waves, BM=64.
__global__ __launch_bounds__(256,4) void k_attn(
    const f16* __restrict__ e16, const f16* __restrict__ valT,
    const float* __restrict__ scores, f16* __restrict__ ti16)
{
  __shared__ f16 buf[2][9216];   // B: 0..7167 (7 duos), A: 7168..9215 (4 halves)
  __shared__ float wsm[64*NEXP];
  const int tid = threadIdx.x, lane = tid & 63, wv = tid >> 6;
  const int l15 = lane & 15, lhi = lane >> 4;
  const int colh = blockIdx.x;
  const int rowbase = blockIdx.y * 64;
  const int nd = colh ? 6 : 7;
  const int nB = nd*2;
  const int t0 = colh * 14;
  const f32x4 Z4 = {0,0,0,0};
  f32x4 acc[14];
  #pragma unroll
  for (int j=0;j<14;j++) acc[j]=Z4;

  if (tid < 64){
    const float* sr = scores + (size_t)(rowbase + tid)*NEXP;
    float s[8]; float m = -1e30f;
    #pragma unroll
    for (int k=0;k<8;k++){ s[k]=sr[k]; m = fmaxf(m, s[k]); }
    float sum = 0.f;
    #pragma unroll
    for (int k=0;k<8;k++){ s[k] = expf(s[k]-m); sum += s[k]; }
    float inv = 1.f/sum;
    #pragma unroll
    for (int k=0;k<8;k++) wsm[tid*NEXP + k] = s[k]*inv;
  }
  LGKM0;

  const char* eb0 = (const char*)e16 + (size_t)rowbase*832;

  // stage(n,kt) into buf: B nd duos + A 4 halves, over 4 waves
  #define STAGE_ATT(n_, k_, BUFC) do {                                          \
    const char* vb_ = (const char*)(valT + (size_t)(n_)*DP*DP);                 \
    const char* ab_ = eb0 + (size_t)(n_)*NB*832;                                \
    int tot_ = nB + 4;                                                          \
    for (int u = wv; u < tot_; u += 4){                                         \
      if (u < nB) stage_duo(vb_, (BUFC), (k_), t0, u>>1, u&1, lane);            \
      else        stage_ah(ab_, (BUFC) + 7*2048, (k_), u-nB, lane);             \
    }                                                                           \
  } while(0)

  STAGE_ATT(0, 0, (char*)buf[0]);
  for (int n=0;n<NEXP;n++){
    for (int kt=0;kt<NKT;kt++){
      int s = n*NKT + kt;
      if (s < NEXP*NKT-1){
        int n2 = (kt==NKT-1)? n+1 : n, k2 = (kt==NKT-1)? 0 : kt+1;
        STAGE_ATT(n2, k2, (char*)buf[(s+1)&1]);
      }
      if (s == NEXP*NKT-1) { VM(0); }
      else if (colh == 0 && wv < 2) { VM(5); }
      else { VM(4); }
      BAR();
      const f16* bb = buf[s&1]; const f16* ba = bb + 7168;
      f16 wn = (f16)wsm[(wv*16+l15)*NEXP + n];
      f16x8 a = rdA(ba, wv*16 + l15, lhi);
      f16x8 as = scale8(a, wn);
      __builtin_amdgcn_s_setprio(1);
      #pragma unroll
      for (int dd=0;dd<7;dd++) if (dd<nd){
        f16x8 b0 = rdB(bb, dd, 0, lhi, l15);
        f16x8 b1 = rdB(bb, dd, 1, lhi, l15);
        acc[dd*2]   = mfma16x32(as, b0, acc[dd*2]);
        acc[dd*2+1] = mfma16x32(as, b1, acc[dd*2+1]);
      }
      __builtin_amdgcn_s_setprio(0);
      BAR();
    }
  }
  #pragma unroll
  for (int dd=0;dd<7;dd++) if (dd<nd)
    #pragma unroll
    for (int t2=0;t2<2;t2++){
      int j = dd*2+t2;
      int col = (t0 + j)*16 + l15;
      #pragma unroll
      for (int rr=0;rr<4;rr++)
        ti16[(size_t)(rowbase + wv*16 + lhi*4 + rr)*DP + col] = (f16)acc[j][rr];
    }
}

__global__ __launch_bounds__(512,2) void k_mlp3(
    const f16* __restrict__ ti16,
    const f16* __restrict__ tw1T, const float* __restrict__ tb1,
    const f16* __restrict__ tw2T, const float* __restrict__ tb2,
    const float* __restrict__ tw3, const float* __restrict__ tb3,
    float* __restrict__ out)
{
  __shared__ f16 bufB[2][13*1024];
  __shared__ f16 lact[128*416];
  __shared__ float psum[128][2];
  const int tid = threadIdx.x, lane = tid & 63, wv = tid >> 6;
  const int l15 = lane & 15, lhi = lane >> 4;
  const int rh = wv >> 1, ch = wv & 1;
  const int rowbase = blockIdx.x * 128;
  const f32x4 Z4 = {0,0,0,0};
  f32x4 acc[2][13];

  // GEMM1: A = ti16 (reg-prefetch, issued AFTER stage so vmcnt count = W+2)
  ZERO_ACC();
  const f16* Ab = ti16 + (size_t)(rowbase + rh*32 + l15)*DP;
  stageB8((const char*)tw1T, (char*)bufB[0], 0, wv, lane);
  MEMFENCE;
  f16x8 a0 = *(const f16x8*)(Ab + lhi*8);
  f16x8 a1 = *(const f16x8*)(Ab + 16*DP + lhi*8);
  for (int kt=0; kt<NKT-1; kt++){
    stageB8((const char*)tw1T, (char*)bufB[(kt+1)&1], kt+1, wv, lane);
    MEMFENCE;
    f16x8 a0n = *(const f16x8*)(Ab + (kt+1)*32 + lhi*8);
    f16x8 a1n = *(const f16x8*)(Ab + 16*DP + (kt+1)*32 + lhi*8);
    if (wv < 2) VM(6); else VM(5);
    BAR();
    MFMA26(a0, a1, bufB[kt&1]);
    BAR();
    a0=a0n; a1=a1n;
  }
  VM(0); BAR();
  MFMA26(a0, a1, bufB[0]);
  BAR();
  stageB8((const char*)tw2T, (char*)bufB[0], 0, wv, lane);
  #pragma unroll
  for (int j=0;j<13;j++){
    int col = (ch*13+j)*16 + l15;
    float bv = (col<D)? tb1[col] : 0.f;
    #pragma unroll
    for (int ar=0;ar<2;ar++)
      #pragma unroll
      for (int rr=0;rr<4;rr++){
        float v = acc[ar][j][rr] + bv; v = v>0.f?v:0.f;
        lact[lact_idx(rh*32+ar*16+lhi*4+rr, col)] = (f16)v;
      }
  }
  LGKM0; BAR();

  // GEMM2: A from lact
  ZERO_ACC();
  for (int kt=0; kt<NKT-1; kt++){
    stageB8((const char*)tw2T, (char*)bufB[(kt+1)&1], kt+1, wv, lane);
    if (wv < 2) VM(4); else VM(3);
    BAR();
    f16x8 ax0 = rdL(lact, rh*32 + l15, kt, lhi);
    f16x8 ax1 = rdL(lact, rh*32 + 16 + l15, kt, lhi);
    MFMA26(ax0, ax1, bufB[kt&1]);
    BAR();
  }
  VM(0); BAR();
  { f16x8 ax0 = rdL(lact, rh*32 + l15, 12, lhi);
    f16x8 ax1 = rdL(lact, rh*32 + 16 + l15, 12, lhi);
    MFMA26(ax0, ax1, bufB[0]); }

  // L3 dot
  float p_[2][4] = {{0,0,0,0},{0,0,0,0}};
  #pragma unroll
  for (int j=0;j<13;j++){
    int col = (ch*13+j)*16 + l15;
    float bv = (col<D)? tb2[col] : 0.f;
    float w3 = (col<D)? tw3[col] : 0.f;
    #pragma unroll
    for (int ar=0;ar<2;ar++)
      #pragma unroll
      for (int rr=0;rr<4;rr++){
        float v = acc[ar][j][rr] + bv; v = v>0.f?v:0.f;
        p_[ar][rr] += v * w3;
      }
  }
  #pragma unroll
  for (int ar=0;ar<2;ar++)
    #pragma unroll
    for (int rr=0;rr<4;rr++){
      float p = p_[ar][rr];
      p += __shfl_xor(p, 1, 64);
      p += __shfl_xor(p, 2, 64);
      p += __shfl_xor(p, 4, 64);
      p += __shfl_xor(p, 8, 64);
      if (l15 == 0) psum[rh*32+ar*16+lhi*4+rr][ch] = p;
    }
  __syncthreads();
  if (tid < 128) out[rowbase + tid] = psum[tid][0] + psum[tid][1] + tb3[0];
}

// ---------------- launcher ----------------

extern "C" void kernel_launch(void* const* d_in, const int* in_sizes, int n_in,
                              void* d_out, int out_size, void* d_ws, size_t ws_size,
                              hipStream_t stream)
{
  const float* obs     = (const float*)d_in[0];
  const float* act     = (const float*)d_in[1];
  const int*   task    = (const int*)  d_in[2];
  const float* bb_w1   = (const float*)d_in[3];
  const float* bb_b1   = (const float*)d_in[4];
  const float* bb_w2   = (const float*)d_in[5];
  const float* bb_b2   = (const float*)d_in[6];
  const float* ex_w1   = (const float*)d_in[7];
  const float* ex_b1   = (const float*)d_in[8];
  const float* ex_w2   = (const float*)d_in[9];
  const float* ex_b2   = (const float*)d_in[10];
  const float* key_mat = (const float*)d_in[11];
  const float* val_mat = (const float*)d_in[12];
  const float* tq      = (const float*)d_in[13];
  const float* tw_w1   = (const float*)d_in[14];
  const float* tw_b1   = (const float*)d_in[15];
  const float* tw_w2   = (const float*)d_in[16];
  const float* tw_b2   = (const float*)d_in[17];
  const float* tw_w3   = (const float*)d_in[18];
  const float* tw_b3   = (const float*)d_in[19];

  char* ws = (char*)d_ws;
  size_t off = 0;
  auto alloc = [&](size_t bytes){ void* p = ws + off; off += (bytes + 255) & ~(size_t)255; return p; };
  f16*   x16   = (f16*)  alloc((size_t)NB*64*2);
  f16*   h16   = (f16*)  alloc((size_t)NB*DP*2);
  f16*   e16   = (f16*)  alloc((size_t)NEXP*NB*DP*2);   // exp1 out; exp2 in-place; attn in
  f16*   ti16  = (f16*)  alloc((size_t)NB*DP*2);
  float* scors = (float*)alloc((size_t)NB*NEXP*4);
  float* kq    = (float*)alloc((size_t)NEXP*NTASK*DP*4);
  f16*   bbw1T = (f16*)  alloc((size_t)DP*64*2);
  f16*   bbw2T = (f16*)  alloc((size_t)DP*DP*2);
  f16*   exw1T = (f16*)  alloc((size_t)NEXP*DP*DP*2);
  f16*   exw2T = (f16*)  alloc((size_t)NEXP*DP*DP*2);
  f16*   valT  = (f16*)  alloc((size_t)NEXP*DP*DP*2);
  f16*   tw1T  = (f16*)  alloc((size_t)DP*DP*2);
  f16*   tw2T  = (f16*)  alloc((size_t)DP*DP*2);
  (void)ws_size; (void)in_sizes; (void)n_in; (void)out_size;

  k_build_x<<<NB*64/256, 256, 0, stream>>>(obs, act, x16);
  k_transpose<<<dim3(13, 2, 1),  256, 0, stream>>>(bb_w1, bbw1T, 43, D, 64, DP);
  k_transpose<<<dim3(13,13, 1),  256, 0, stream>>>(bb_w2, bbw2T, D, D, DP, DP);
  k_transpose<<<dim3(13,13, 8),  256, 0, stream>>>(ex_w1, exw1T, D, D, DP, DP);
  k_transpose<<<dim3(13,13, 8),  256, 0, stream>>>(ex_w2, exw2T, D, D, DP, DP);
  k_transpose<<<dim3(13,13, 1),  256, 0, stream>>>(tw_w1, tw1T,  D, D, DP, DP);
  k_transpose<<<dim3(13,13, 1),  256, 0, stream>>>(tw_w2, tw2T,  D, D, DP, DP);
  k_val_pad<<<(NEXP*DP*DP + 255)/256, 256, 0, stream>>>(val_mat, valT);
  k_kq<<<NEXP, 256, 0, stream>>>(key_mat, tq, kq);

  k_backbone<<<NB/128, 512, 0, stream>>>(x16, bbw1T, bb_b1, bbw2T, bb_b2, h16);
  k_exp1<<<dim3(NEXP, NB/128), 512, 0, stream>>>(h16, exw1T, ex_b1, e16);
  k_exp2<<<dim3(NEXP, NB/128), 512, 0, stream>>>(e16, exw2T, ex_b2, kq, task, scors);
  k_attn<<<dim3(2, NB/64), 256, 0, stream>>>(e16, valT, scors, ti16);
  k_mlp3<<<NB/128, 512, 0, stream>>>(ti16, tw1T, tw_b1, tw2T, tw_b2, tw_w3, tw_b3,
                                     (float*)d_out);
}

// Round 6
// 427.501 us; speedup vs baseline: 2.8181x; 2.8181x over previous
//
#include <hip/hip_runtime.h>

typedef _Float16 f16;
typedef f16 f16x8 __attribute__((ext_vector_type(8)));
typedef float f32x4 __attribute__((ext_vector_type(4)));

#define NB 16384
#define D 400
#define DP 416
#define NEXP 8
#define NTASK 10
#define NKT 13

#define MEMFENCE asm volatile("" ::: "memory")
#define BAR() do{ MEMFENCE; __builtin_amdgcn_s_barrier(); MEMFENCE; }while(0)
#define VM(N) asm volatile("s_waitcnt vmcnt(" #N ")" ::: "memory")
#define LGKM0 asm volatile("s_waitcnt lgkmcnt(0)" ::: "memory")

static __device__ __forceinline__ f32x4 mfma16x32(f16x8 a, f16x8 b, f32x4 c){
  return __builtin_amdgcn_mfma_f32_16x16x32_f16(a, b, c, 0, 0, 0);
}
static __device__ __forceinline__ void g2l(const void* g, void* l){
  __builtin_amdgcn_global_load_lds((const __attribute__((address_space(1))) void*)g,
      (__attribute__((address_space(3))) void*)l, 16, 0, 0);
}
static __device__ __forceinline__ f16x8 scale8(f16x8 a, f16 s){
  f16x8 r;
  #pragma unroll
  for (int e=0;e<8;e++) r[e] = a[e]*s;
  return r;
}

// ---- swizzled duo staging (verified R4) ------------------------------------
// duo = two adjacent 16-col j-tiles for one kt: [16 rows][128B], chunk ^= row&7.
// LDS dest linear (g2l lane scatter); global source pre-swizzled.
static __device__ __forceinline__ void stage_duo(const char* wbase, char* lds, int kt,
                                                 int t0, int dd, int h, int lane){
  const int r = lane >> 3, c = lane & 7, cg = c ^ r;
  g2l(wbase + (size_t)((t0 + dd*2 + (cg>>2))*16 + h*8 + r)*832 + (size_t)kt*64 + (cg&3)*16,
      lds + dd*2048 + h*1024);
}
// B-frag read: duo dloc, parity t; lane: col=l15, k=lhi*8+e
static __device__ __forceinline__ f16x8 rdB(const f16* buf, int dloc, int t, int lhi, int l15){
  return *(const f16x8*)(buf + dloc*1024 + l15*64 + ((((t*4+lhi) ^ (l15&7)))<<3));
}
// lact: [128][416] f16, 16B-chunk XOR swizzle on chunks<48
static __device__ __forceinline__ f16x8 rdL(const f16* lact, int r, int kt, int lhi){
  int q = kt*4 + lhi;
  int c = (q < 48) ? (q ^ (r&7)) : q;
  return *(const f16x8*)(lact + r*416 + (c<<3));
}
static __device__ __forceinline__ int lact_idx(int r, int col){
  int q = col >> 3;
  int c = (q < 48) ? (q ^ (r&7)) : q;
  return r*416 + (c<<3) + (col&7);
}
// B-only staging: 26 halves over 8 waves (waves 0,1: 4 loads; 2..7: 3 loads)
static __device__ __forceinline__ void stageB8(const char* wb, char* buf, int kt,
                                               int wv, int lane){
  for (int u = wv; u < 26; u += 8) stage_duo(wb, buf, kt, 0, u>>1, u&1, lane);
}

// ---------------- prep kernels ----------------

__global__ void k_build_x(const float* __restrict__ obs, const float* __restrict__ act,
                          f16* __restrict__ x)
{
  int idx = blockIdx.x*256 + threadIdx.x;
  int b = idx >> 6, c = idx & 63;
  float v = 0.f;
  if (c < 39) v = obs[b*39 + c];
  else if (c < 43) v = act[b*4 + (c - 39)];
  x[idx] = (f16)v;
}

__global__ void k_transpose(const float* __restrict__ in, f16* __restrict__ out,
                            int K, int N, int Kpad, int Npad)
{
  __shared__ float t[32][33];
  int tx = threadIdx.x & 31, ty = threadIdx.x >> 5;
  int n0 = blockIdx.x*32, k0 = blockIdx.y*32;
  in  += (size_t)blockIdx.z * K * N;
  out += (size_t)blockIdx.z * Npad * Kpad;
  #pragma unroll
  for (int r=0;r<4;r++){
    int k = k0 + ty + r*8, nn = n0 + tx;
    t[ty + r*8][tx] = (k < K && nn < N) ? in[(size_t)k*N + nn] : 0.f;
  }
  __syncthreads();
  #pragma unroll
  for (int r=0;r<4;r++){
    int nn = n0 + ty + r*8, kp = k0 + tx;
    if (nn < Npad && kp < Kpad) out[(size_t)nn*Kpad + kp] = (f16)t[tx][ty + r*8];
  }
}

__global__ void k_val_pad(const float* __restrict__ in, f16* __restrict__ out)
{
  int idx = blockIdx.x*256 + threadIdx.x;
  if (idx >= NEXP*DP*DP) return;
  int c = idx % DP, r = (idx / DP) % DP, n = idx / (DP*DP);
  float v = (r < D && c < D) ? in[((size_t)n*D + r)*D + c] : 0.f;
  out[idx] = (f16)v;
}

__global__ void k_kq(const float* __restrict__ key_mat, const float* __restrict__ tq,
                     float* __restrict__ kq)
{
  __shared__ float tqs[NTASK*D];
  int n = blockIdx.x, tid = threadIdx.x;
  for (int i=tid;i<NTASK*D;i+=256) tqs[i] = tq[i];
  __syncthreads();
  float a0[NTASK], a1[NTASK];
  #pragma unroll
  for (int t=0;t<NTASK;t++){ a0[t]=0.f; a1[t]=0.f; }
  const float* km = key_mat + (size_t)n*D*D;
  for (int i=0;i<D;i++){
    float v0 = km[(size_t)i*D + tid];
    float v1 = (tid+256 < D) ? km[(size_t)i*D + tid + 256] : 0.f;
    #pragma unroll
    for (int t=0;t<NTASK;t++){
      float q = tqs[t*D + i];
      a0[t] += v0*q; a1[t] += v1*q;
    }
  }
  #pragma unroll
  for (int t=0;t<NTASK;t++){
    kq[(size_t)n*NTASK*DP + t*DP + tid] = a0[t];
    if (tid+256 < DP) kq[(size_t)n*NTASK*DP + t*DP + tid+256] = (tid+256 < D) ? a1[t] : 0.f;
  }
}

// ---------------- compute kernels ----------------
// 512 thr = 8 waves, BM=128. wave (rh=wv>>1, ch=wv&1): rows rh*32..+31, tiles ch*13..+12.

#define ZERO_ACC() do { _Pragma("unroll") for (int j=0;j<13;j++){ acc[0][j]=Z4; acc[1][j]=Z4; } } while(0)

#define MFMA26(a0_, a1_, BUF) do {                                              \
    __builtin_amdgcn_s_setprio(1);                                              \
    _Pragma("unroll")                                                           \
    for (int j=0;j<13;j++){                                                     \
      int tj = ch*13 + j;                                                       \
      f16x8 b = rdB((BUF), tj>>1, tj&1, lhi, l15);                              \
      acc[0][j] = mfma16x32((a0_), b, acc[0][j]);                               \
      acc[1][j] = mfma16x32((a1_), b, acc[1][j]);                               \
    }                                                                           \
    __builtin_amdgcn_s_setprio(0);                                              \
  } while(0)

__global__ __launch_bounds__(512,2) void k_backbone(
    const f16* __restrict__ x, const f16* __restrict__ w1T, const float* __restrict__ b1,
    const f16* __restrict__ w2T, const float* __restrict__ b2, f16* __restrict__ h16)
{
  __shared__ f16 bufB[2][13*1024];
  __shared__ f16 lact[128*416];
  const int tid = threadIdx.x, lane = tid & 63, wv = tid >> 6;
  const int l15 = lane & 15, lhi = lane >> 4;
  const int rh = wv >> 1, ch = wv & 1;
  const int rowbase = blockIdx.x * 128;
  const f32x4 Z4 = {0,0,0,0};
  f32x4 acc[2][13];

  // GEMM1: K=64. stage all 26 tiles flat (2KB each) across bufB[0]+bufB[1]
  { int r = lane>>3, c = lane&7, cg = c ^ r;
    for (int u = wv; u < 52; u += 8){
      int dd = u>>1, h = u&1;
      g2l((const char*)w1T + (size_t)(dd*16 + h*8 + r)*128 + cg*16,
          (char*)bufB[0] + dd*2048 + h*1024);
    }
  }
  ZERO_ACC();
  const f16* Ab = x + (size_t)(rowbase + rh*32 + l15)*64;
  __syncthreads();
  #pragma unroll
  for (int kt=0; kt<2; kt++){
    f16x8 a0 = *(const f16x8*)(Ab + kt*32 + lhi*8);
    f16x8 a1 = *(const f16x8*)(Ab + 16*64 + kt*32 + lhi*8);
    __builtin_amdgcn_s_setprio(1);
    #pragma unroll
    for (int j=0;j<13;j++){
      int tj = ch*13 + j;
      f16x8 b = rdB(bufB[0], tj, kt, lhi, l15);
      acc[0][j] = mfma16x32(a0, b, acc[0][j]);
      acc[1][j] = mfma16x32(a1, b, acc[1][j]);
    }
    __builtin_amdgcn_s_setprio(0);
  }
  BAR();                                  // all waves done reading GEMM1 tiles
  stageB8((const char*)w2T, (char*)bufB[0], 0, wv, lane);
  #pragma unroll
  for (int j=0;j<13;j++){
    int col = (ch*13+j)*16 + l15;
    float bv = (col<D)? b1[col] : 0.f;
    #pragma unroll
    for (int ar=0;ar<2;ar++)
      #pragma unroll
      for (int rr=0;rr<4;rr++){
        float v = acc[ar][j][rr] + bv; v = v>0.f?v:0.f;
        lact[lact_idx(rh*32+ar*16+lhi*4+rr, col)] = (f16)v;
      }
  }
  LGKM0;                                  // lact writes retired (published at next BAR)

  // GEMM2: K=416, counted-vmcnt 2-barrier loop
  ZERO_ACC();
  for (int kt=0; kt<NKT; kt++){
    if (kt < NKT-1){
      stageB8((const char*)w2T, (char*)bufB[(kt+1)&1], kt+1, wv, lane);
      if (wv < 2) VM(4); else VM(3);
    } else VM(0);
    BAR();
    f16x8 a0 = rdL(lact, rh*32 + l15, kt, lhi);
    f16x8 a1 = rdL(lact, rh*32 + 16 + l15, kt, lhi);
    MFMA26(a0, a1, bufB[kt&1]);
    BAR();
  }
  #pragma unroll
  for (int j=0;j<13;j++){
    int col = (ch*13+j)*16 + l15;
    float bv = (col<D)? b2[col] : 0.f;
    #pragma unroll
    for (int ar=0;ar<2;ar++)
      #pragma unroll
      for (int rr=0;rr<4;rr++){
        float v = acc[ar][j][rr] + bv; v = v>0.f?v:0.f;
        h16[(size_t)(rowbase + rh*32+ar*16+lhi*4+rr)*DP + col] = (f16)v;
      }
  }
}

__global__ __launch_bounds__(512,2) void k_experts(
    const f16* __restrict__ h16, const f16* __restrict__ w1T, const float* __restrict__ b1s,
    const f16* __restrict__ w2T, const float* __restrict__ b2s,
    f16* __restrict__ e16, const float* __restrict__ kqg, const int* __restrict__ task,
    float* __restrict__ scores)
{
  __shared__ f16 bufB[2][13*1024];
  __shared__ f16 lact[128*416];
  __shared__ float psum[128][2];
  const int tid = threadIdx.x, lane = tid & 63, wv = tid >> 6;
  const int l15 = lane & 15, lhi = lane >> 4;
  const int rh = wv >> 1, ch = wv & 1;
  const int n = blockIdx.x;
  const int rowbase = blockIdx.y * 128;
  const f32x4 Z4 = {0,0,0,0};
  f32x4 acc[2][13];

  const char* wb1 = (const char*)(w1T + (size_t)n*DP*DP);
  const char* wb2 = (const char*)(w2T + (size_t)n*DP*DP);

  // GEMM1: A = h16 (reg-prefetch), B staged; counted-vmcnt 2-barrier
  ZERO_ACC();
  stageB8(wb1, (char*)bufB[0], 0, wv, lane);
  const f16* Ab = h16 + (size_t)(rowbase + rh*32 + l15)*DP;
  f16x8 a0 = *(const f16x8*)(Ab + lhi*8);
  f16x8 a1 = *(const f16x8*)(Ab + 16*DP + lhi*8);
  for (int kt=0; kt<NKT; kt++){
    f16x8 a0n=a0, a1n=a1;
    if (kt < NKT-1){
      stageB8(wb1, (char*)bufB[(kt+1)&1], kt+1, wv, lane);
      a0n = *(const f16x8*)(Ab + (kt+1)*32 + lhi*8);
      a1n = *(const f16x8*)(Ab + 16*DP + (kt+1)*32 + lhi*8);
      if (wv < 2) VM(6); else VM(5);      // leave kt+1's (4|3 B + 2 A) in flight
    } else VM(0);
    BAR();
    MFMA26(a0, a1, bufB[kt&1]);
    BAR();
    a0=a0n; a1=a1n;
  }
  stageB8(wb2, (char*)bufB[0], 0, wv, lane);
  #pragma unroll
  for (int j=0;j<13;j++){
    int col = (ch*13+j)*16 + l15;
    float bv = (col<D)? b1s[n*D+col] : 0.f;
    #pragma unroll
    for (int ar=0;ar<2;ar++)
      #pragma unroll
      for (int rr=0;rr<4;rr++){
        float v = acc[ar][j][rr] + bv; v = v>0.f?v:0.f;
        lact[lact_idx(rh*32+ar*16+lhi*4+rr, col)] = (f16)v;
      }
  }
  LGKM0;

  // GEMM2: A from lact; counted-vmcnt 2-barrier
  ZERO_ACC();
  for (int kt=0; kt<NKT; kt++){
    if (kt < NKT-1){
      stageB8(wb2, (char*)bufB[(kt+1)&1], kt+1, wv, lane);
      if (wv < 2) VM(4); else VM(3);
    } else VM(0);
    BAR();
    f16x8 ax0 = rdL(lact, rh*32 + l15, kt, lhi);
    f16x8 ax1 = rdL(lact, rh*32 + 16 + l15, kt, lhi);
    MFMA26(ax0, ax1, bufB[kt&1]);
    BAR();
  }
  // epilogue: e16 + score partials
  const float* kqp[2][4];
  const float* kqb = kqg + (size_t)n*NTASK*DP;
  #pragma unroll
  for (int ar=0;ar<2;ar++)
    #pragma unroll
    for (int rr=0;rr<4;rr++){
      int grow = rowbase + rh*32 + ar*16 + lhi*4 + rr;
      kqp[ar][rr] = kqb + (size_t)task[grow]*DP;
    }
  float p_[2][4] = {{0,0,0,0},{0,0,0,0}};
  #pragma unroll
  for (int j=0;j<13;j++){
    int col = (ch*13+j)*16 + l15;
    float bv = (col<D)? b2s[n*D+col] : 0.f;
    #pragma unroll
    for (int ar=0;ar<2;ar++)
      #pragma unroll
      for (int rr=0;rr<4;rr++){
        float v = acc[ar][j][rr] + bv; v = v>0.f?v:0.f;
        e16[((size_t)n*NB + rowbase + rh*32+ar*16+lhi*4+rr)*DP + col] = (f16)v;
        p_[ar][rr] += v * kqp[ar][rr][col];
      }
  }
  #pragma unroll
  for (int ar=0;ar<2;ar++)
    #pragma unroll
    for (int rr=0;rr<4;rr++){
      float p = p_[ar][rr];
      p += __shfl_xor(p, 1, 64);
      p += __shfl_xor(p, 2, 64);
      p += __shfl_xor(p, 4, 64);
      p += __shfl_xor(p, 8, 64);
      if (l15 == 0) psum[rh*32+ar*16+lhi*4+rr][ch] = p;
    }
  __syncthreads();
  if (tid < 128) scores[(size_t)(rowbase + tid)*NEXP + n] = psum[tid][0] + psum[tid][1];
}

// attn: softmax + 8 weighted value-GEMMs -> ti16. 256 thr, 4 waves, BM=64.
__global__ __launch_bounds__(256,4) void k_attn(
    const f16* __restrict__ e16, const f16* __restrict__ valT,
    const float* __restrict__ scores, f16* __restrict__ ti16)
{
  __shared__ f16 bufB[2][7*1024];
  __shared__ float wsm[64*NEXP];
  const int tid = threadIdx.x, lane = tid & 63, wv = tid >> 6;
  const int l15 = lane & 15, lhi = lane >> 4;
  const int colh = blockIdx.x;
  const int rowbase = blockIdx.y * 64;
  const int nd = colh ? 6 : 7;
  const int nB = nd*2;
  const int t0 = colh * 14;
  const f32x4 Z4 = {0,0,0,0};
  f32x4 acc[14];
  #pragma unroll
  for (int j=0;j<14;j++) acc[j]=Z4;

  if (tid < 64){
    const float* sr = scores + (size_t)(rowbase + tid)*NEXP;
    float s[8]; float m = -1e30f;
    #pragma unroll
    for (int k=0;k<8;k++){ s[k]=sr[k]; m = fmaxf(m, s[k]); }
    float sum = 0.f;
    #pragma unroll
    for (int k=0;k<8;k++){ s[k] = expf(s[k]-m); sum += s[k]; }
    float inv = 1.f/sum;
    #pragma unroll
    for (int k=0;k<8;k++) wsm[tid*NEXP + k] = s[k]*inv;
  }

  const f16* Arow = e16 + (size_t)(rowbase + wv*16 + l15)*DP;

  #define STAGE_V(n_, k_, BUFC) do {                                            \
    const char* vb_ = (const char*)(valT + (size_t)(n_)*DP*DP);                 \
    for (int u = wv; u < nB; u += 4)                                            \
      stage_duo(vb_, (BUFC), (k_), t0, u>>1, u&1, lane);                        \
  } while(0)

  STAGE_V(0, 0, (char*)bufB[0]);
  f16x8 a = *(const f16x8*)(Arow + lhi*8);
  LGKM0; BAR();                           // wsm visible; kt0 prefetch NOT drained

  for (int n=0;n<NEXP;n++){
    for (int kt=0;kt<NKT;kt++){
      int s = n*NKT + kt;
      f16x8 an = a;
      if (s < NEXP*NKT-1){
        int n2 = (kt==NKT-1)? n+1 : n, k2 = (kt==NKT-1)? 0 : kt+1;
        STAGE_V(n2, k2, (char*)bufB[(s+1)&1]);
        an = *(const f16x8*)(Arow + (size_t)n2*NB*DP + k2*32 + lhi*8);
        if (colh == 0 && wv < 2) { VM(5); } else { VM(4); }   // leave s+1's (4|3 B + 1 A)
      } else { VM(0); }
      BAR();
      const f16* bb = bufB[s&1];
      f16 wn = (f16)wsm[(wv*16+l15)*NEXP + n];
      f16x8 as = scale8(a, wn);
      __builtin_amdgcn_s_setprio(1);
      #pragma unroll
      for (int dd=0;dd<7;dd++) if (dd<nd){
        f16x8 b0 = rdB(bb, dd, 0, lhi, l15);
        f16x8 b1 = rdB(bb, dd, 1, lhi, l15);
        acc[dd*2]   = mfma16x32(as, b0, acc[dd*2]);
        acc[dd*2+1] = mfma16x32(as, b1, acc[dd*2+1]);
      }
      __builtin_amdgcn_s_setprio(0);
      BAR();
      a = an;
    }
  }
  #pragma unroll
  for (int dd=0;dd<7;dd++) if (dd<nd)
    #pragma unroll
    for (int t2=0;t2<2;t2++){
      int j = dd*2+t2;
      int col = (t0 + j)*16 + l15;
      #pragma unroll
      for (int rr=0;rr<4;rr++)
        ti16[(size_t)(rowbase + wv*16 + lhi*4 + rr)*DP + col] = (f16)acc[j][rr];
    }
}

__global__ __launch_bounds__(512,2) void k_mlp3(
    const f16* __restrict__ ti16,
    const f16* __restrict__ tw1T, const float* __restrict__ tb1,
    const f16* __restrict__ tw2T, const float* __restrict__ tb2,
    const float* __restrict__ tw3, const float* __restrict__ tb3,
    float* __restrict__ out)
{
  __shared__ f16 bufB[2][13*1024];
  __shared__ f16 lact[128*416];
  __shared__ float psum[128][2];
  const int tid = threadIdx.x, lane = tid & 63, wv = tid >> 6;
  const int l15 = lane & 15, lhi = lane >> 4;
  const int rh = wv >> 1, ch = wv & 1;
  const int rowbase = blockIdx.x * 128;
  const f32x4 Z4 = {0,0,0,0};
  f32x4 acc[2][13];

  // GEMM1: A = ti16 (reg-prefetch)
  ZERO_ACC();
  stageB8((const char*)tw1T, (char*)bufB[0], 0, wv, lane);
  const f16* Ab = ti16 + (size_t)(rowbase + rh*32 + l15)*DP;
  f16x8 a0 = *(const f16x8*)(Ab + lhi*8);
  f16x8 a1 = *(const f16x8*)(Ab + 16*DP + lhi*8);
  for (int kt=0; kt<NKT; kt++){
    f16x8 a0n=a0, a1n=a1;
    if (kt < NKT-1){
      stageB8((const char*)tw1T, (char*)bufB[(kt+1)&1], kt+1, wv, lane);
      a0n = *(const f16x8*)(Ab + (kt+1)*32 + lhi*8);
      a1n = *(const f16x8*)(Ab + 16*DP + (kt+1)*32 + lhi*8);
      if (wv < 2) VM(6); else VM(5);
    } else VM(0);
    BAR();
    MFMA26(a0, a1, bufB[kt&1]);
    BAR();
    a0=a0n; a1=a1n;
  }
  stageB8((const char*)tw2T, (char*)bufB[0], 0, wv, lane);
  #pragma unroll
  for (int j=0;j<13;j++){
    int col = (ch*13+j)*16 + l15;
    float bv = (col<D)? tb1[col] : 0.f;
    #pragma unroll
    for (int ar=0;ar<2;ar++)
      #pragma unroll
      for (int rr=0;rr<4;rr++){
        float v = acc[ar][j][rr] + bv; v = v>0.f?v:0.f;
        lact[lact_idx(rh*32+ar*16+lhi*4+rr, col)] = (f16)v;
      }
  }
  LGKM0;

  // GEMM2: A from lact
  ZERO_ACC();
  for (int kt=0; kt<NKT; kt++){
    if (kt < NKT-1){
      stageB8((const char*)tw2T, (char*)bufB[(kt+1)&1], kt+1, wv, lane);
      if (wv < 2) VM(4); else VM(3);
    } else VM(0);
    BAR();
    f16x8 ax0 = rdL(lact, rh*32 + l15, kt, lhi);
    f16x8 ax1 = rdL(lact, rh*32 + 16 + l15, kt, lhi);
    MFMA26(ax0, ax1, bufB[kt&1]);
    BAR();
  }
  // L3 dot
  float p_[2][4] = {{0,0,0,0},{0,0,0,0}};
  #pragma unroll
  for (int j=0;j<13;j++){
    int col = (ch*13+j)*16 + l15;
    float bv = (col<D)? tb2[col] : 0.f;
    float w3 = (col<D)? tw3[col] : 0.f;
    #pragma unroll
    for (int ar=0;ar<2;ar++)
      #pragma unroll
      for (int rr=0;rr<4;rr++){
        float v = acc[ar][j][rr] + bv; v = v>0.f?v:0.f;
        p_[ar][rr] += v * w3;
      }
  }
  #pragma unroll
  for (int ar=0;ar<2;ar++)
    #pragma unroll
    for (int rr=0;rr<4;rr++){
      float p = p_[ar][rr];
      p += __shfl_xor(p, 1, 64);
      p += __shfl_xor(p, 2, 64);
      p += __shfl_xor(p, 4, 64);
      p += __shfl_xor(p, 8, 64);
      if (l15 == 0) psum[rh*32+ar*16+lhi*4+rr][ch] = p;
    }
  __syncthreads();
  if (tid < 128) out[rowbase + tid] = psum[tid][0] + psum[tid][1] + tb3[0];
}

// ---------------- launcher ----------------

extern "C" void kernel_launch(void* const* d_in, const int* in_sizes, int n_in,
                              void* d_out, int out_size, void* d_ws, size_t ws_size,
                              hipStream_t stream)
{
  const float* obs     = (const float*)d_in[0];
  const float* act     = (const float*)d_in[1];
  const int*   task    = (const int*)  d_in[2];
  const float* bb_w1   = (const float*)d_in[3];
  const float* bb_b1   = (const float*)d_in[4];
  const float* bb_w2   = (const float*)d_in[5];
  const float* bb_b2   = (const float*)d_in[6];
  const float* ex_w1   = (const float*)d_in[7];
  const float* ex_b1   = (const float*)d_in[8];
  const float* ex_w2   = (const float*)d_in[9];
  const float* ex_b2   = (const float*)d_in[10];
  const float* key_mat = (const float*)d_in[11];
  const float* val_mat = (const float*)d_in[12];
  const float* tq      = (const float*)d_in[13];
  const float* tw_w1   = (const float*)d_in[14];
  const float* tw_b1   = (const float*)d_in[15];
  const float* tw_w2   = (const float*)d_in[16];
  const float* tw_b2   = (const float*)d_in[17];
  const float* tw_w3   = (const float*)d_in[18];
  const float* tw_b3   = (const float*)d_in[19];

  char* ws = (char*)d_ws;
  size_t off = 0;
  auto alloc = [&](size_t bytes){ void* p = ws + off; off += (bytes + 255) & ~(size_t)255; return p; };
  f16*   x16   = (f16*)  alloc((size_t)NB*64*2);
  f16*   h16   = (f16*)  alloc((size_t)NB*DP*2);
  f16*   e16   = (f16*)  alloc((size_t)NEXP*NB*DP*2);
  f16*   ti16  = (f16*)  alloc((size_t)NB*DP*2);
  float* scors = (float*)alloc((size_t)NB*NEXP*4);
  float* kq    = (float*)alloc((size_t)NEXP*NTASK*DP*4);
  f16*   bbw1T = (f16*)  alloc((size_t)DP*64*2);
  f16*   bbw2T = (f16*)  alloc((size_t)DP*DP*2);
  f16*   exw1T = (f16*)  alloc((size_t)NEXP*DP*DP*2);
  f16*   exw2T = (f16*)  alloc((size_t)NEXP*DP*DP*2);
  f16*   valT  = (f16*)  alloc((size_t)NEXP*DP*DP*2);
  f16*   tw1T  = (f16*)  alloc((size_t)DP*DP*2);
  f16*   tw2T  = (f16*)  alloc((size_t)DP*DP*2);
  (void)ws_size; (void)in_sizes; (void)n_in; (void)out_size;

  k_build_x<<<NB*64/256, 256, 0, stream>>>(obs, act, x16);
  k_transpose<<<dim3(13, 2, 1),  256, 0, stream>>>(bb_w1, bbw1T, 43, D, 64, DP);
  k_transpose<<<dim3(13,13, 1),  256, 0, stream>>>(bb_w2, bbw2T, D, D, DP, DP);
  k_transpose<<<dim3(13,13, 8),  256, 0, stream>>>(ex_w1, exw1T, D, D, DP, DP);
  k_transpose<<<dim3(13,13, 8),  256, 0, stream>>>(ex_w2, exw2T, D, D, DP, DP);
  k_transpose<<<dim3(13,13, 1),  256, 0, stream>>>(tw_w1, tw1T,  D, D, DP, DP);
  k_transpose<<<dim3(13,13, 1),  256, 0, stream>>>(tw_w2, tw2T,  D, D, DP, DP);
  k_val_pad<<<(NEXP*DP*DP + 255)/256, 256, 0, stream>>>(val_mat, valT);
  k_kq<<<NEXP, 256, 0, stream>>>(key_mat, tq, kq);

  k_backbone<<<NB/128, 512, 0, stream>>>(x16, bbw1T, bb_b1, bbw2T, bb_b2, h16);
  k_experts<<<dim3(NEXP, NB/128), 512, 0, stream>>>(h16, exw1T, ex_b1, exw2T, ex_b2,
                                                    e16, kq, task, scors);
  k_attn<<<dim3(2, NB/64), 256, 0, stream>>>(e16, valT, scors, ti16);
  k_mlp3<<<NB/128, 512, 0, stream>>>(ti16, tw1T, tw_b1, tw2T, tw_b2, tw_w3, tw_b3,
                                     (float*)d_out);
}